// Round 2
// baseline (1374.251 us; speedup 1.0000x reference)
//
#include <hip/hip_runtime.h>
#include <math.h>

#define K_EMB 1024
#define D_DIM 256
#define B_SZ 32
#define T_SZ 2048
#define TOT 16777216        // B*D*T
#define LOSS_OFF 16777216
#define IDX_OFF 16777217
#define MARGIN 1e-2f

// --- Kernel 0: per-code squared norms -------------------------------------
__global__ __launch_bounds__(256) void esq_kernel(const float* __restrict__ E,
                                                  float* __restrict__ esq) {
    int k = blockIdx.x * 4 + (threadIdx.x >> 6);
    int lane = threadIdx.x & 63;
    const float* er = E + (size_t)k * D_DIM;
    float s = 0.f;
#pragma unroll
    for (int i = 0; i < 4; ++i) { float v = er[lane + 64 * i]; s = fmaf(v, v, s); }
#pragma unroll
    for (int off = 32; off > 0; off >>= 1) s += __shfl_down(s, off, 64);
    if (lane == 0) esq[k] = s;
}

// --- Kernel 1: argmin over codebook (fp32 + fp64 refine on near-ties) -----
// block: 256 thr = 4 waves; tile: 64 t. Wave w handles k in [w*256,(w+1)*256).
// x staged in LDS [d][t] (2-way bank alias = free). Codebook rows read via
// wave-uniform scalar loads (k uniform) -> s_load, FMA:ds_read = 16:1.
// Index written to d_out as FLOAT (whole out buffer is read as fp32).
__global__ __launch_bounds__(256, 2) void argmin_kernel(const float* __restrict__ X,
        const float* __restrict__ E, const float* __restrict__ esq,
        float* __restrict__ idxf_out) {
    __shared__ float x_lds[D_DIM * 64];   // 64 KiB; reused for the reduce
    int tid = threadIdx.x;
    int lane = tid & 63;
    int w = tid >> 6;
    int b = blockIdx.x >> 5;
    int t0 = (blockIdx.x & 31) << 6;

    const float* xbase = X + (size_t)b * D_DIM * T_SZ + t0;
    for (int d = w; d < D_DIM; d += 4)
        x_lds[d * 64 + lane] = xbase[(size_t)d * T_SZ + lane];
    __syncthreads();

    // ||x||^2 for this thread's t (= lane)
    float x2 = 0.f;
    for (int d = 0; d < D_DIM; ++d) {
        float xv = x_lds[d * 64 + lane];
        x2 = fmaf(xv, xv, x2);
    }

    int wk = __builtin_amdgcn_readfirstlane(w);   // force wave-uniform k base
    float b1v = INFINITY, b2v = INFINITY;
    int b1k = 0, b2k = 0;

    for (int kb = 0; kb < 16; ++kb) {
        int k0 = wk * 256 + kb * 16;
        const float* eb = E + (size_t)k0 * D_DIM;   // uniform -> s_load
        float acc[16];
#pragma unroll
        for (int u = 0; u < 16; ++u) acc[u] = 0.f;
#pragma unroll 2
        for (int d = 0; d < D_DIM; d += 2) {
            float xv0 = x_lds[d * 64 + lane];
            float xv1 = x_lds[(d + 1) * 64 + lane];
#pragma unroll
            for (int u = 0; u < 16; ++u) {
                acc[u] = fmaf(xv0, eb[u * D_DIM + d],     acc[u]);
                acc[u] = fmaf(xv1, eb[u * D_DIM + d + 1], acc[u]);
            }
        }
#pragma unroll
        for (int u = 0; u < 16; ++u) {
            int k = k0 + u;
            float s = (x2 + esq[k]) - 2.f * acc[u];   // same structure as ref
            if (s < b1v) { b2v = b1v; b2k = b1k; b1v = s; b1k = k; }   // strict <:
            else if (s < b2v) { b2v = s; b2k = k; }                    // first-min wins
        }
    }

    __syncthreads();                       // everyone done with x_lds
    float* redf = x_lds;                   // reuse LDS for cross-wave top-2
    int*   redi = (int*)x_lds;
    redf[w * 64 + lane]        = b1v;
    redf[256 + w * 64 + lane]  = b2v;
    redi[512 + w * 64 + lane]  = b1k;
    redi[768 + w * 64 + lane]  = b2k;
    __syncthreads();

    if (tid < 64) {
        int t = tid;
        float g1v = INFINITY, g2v = INFINITY;
        int g1k = 0, g2k = 0;
#pragma unroll
        for (int ww = 0; ww < 4; ++ww) {   // ascending k order -> ties keep smallest k
            float v1 = redf[ww * 64 + t];       int k1 = redi[512 + ww * 64 + t];
            float v2 = redf[256 + ww * 64 + t]; int k2 = redi[768 + ww * 64 + t];
            if (v1 < g1v) { g2v = g1v; g2k = g1k; g1v = v1; g1k = k1; }
            else if (v1 < g2v) { g2v = v1; g2k = k1; }
            if (v2 < g1v) { g2v = g1v; g2k = g1k; g1v = v2; g1k = k2; }
            else if (v2 < g2v) { g2v = v2; g2k = k2; }
        }
        int idx = g1k;
        if (g2v - g1v < MARGIN) {
            // near-tie: decide with exact fp64 distances (x from global, rare)
            const float* e1 = E + (size_t)g1k * D_DIM;
            const float* e2 = E + (size_t)g2k * D_DIM;
            const float* xc = X + (size_t)b * D_DIM * T_SZ + t0 + t;
            double d1 = 0.0, d2 = 0.0;
            for (int d = 0; d < D_DIM; ++d) {
                double xd = (double)xc[(size_t)d * T_SZ];
                double u1 = xd - (double)e1[d];
                double u2 = xd - (double)e2[d];
                d1 += u1 * u1;
                d2 += u2 * u2;
            }
            if (d2 < d1 || (d2 == d1 && g2k < g1k)) idx = g2k;
        }
        idxf_out[(size_t)b * T_SZ + t0 + t] = (float)idx;   // FLOAT, not int bits
    }
}

// --- Kernel 2: gather quantized, write out0 [B,D,T], commitment loss ------
// 32-t tile; codebook rows staged coalesced into LDS ([t][257] pad -> no
// bank conflicts); X read / out0 write coalesced over t.
__global__ __launch_bounds__(256) void gather_kernel(const float* __restrict__ X,
        const float* __restrict__ E, const float* __restrict__ idxf_in,
        float* __restrict__ out0, float* __restrict__ loss) {
    __shared__ float q_lds[32][D_DIM + 1];
    int tid = threadIdx.x;
    int b = blockIdx.x >> 6;            // 64 chunks of 32 t per b
    int t0 = (blockIdx.x & 63) << 5;
    size_t n0 = (size_t)b * T_SZ + t0;

    for (int tt = 0; tt < 32; ++tt) {
        int row = (int)idxf_in[n0 + tt];    // stored as float value
        q_lds[tt][tid] = E[(size_t)row * D_DIM + tid];   // coalesced 1 KiB
    }
    __syncthreads();

    int t  = tid & 31;
    int dg = tid >> 5;                  // 0..7
    size_t base = (size_t)b * D_DIM * T_SZ + t0 + t;
    float lsum = 0.f;
    for (int d = dg; d < D_DIM; d += 8) {
        float qv = q_lds[t][d];
        float xv = X[base + (size_t)d * T_SZ];
        out0[base + (size_t)d * T_SZ] = qv;   // STE: x + (q-x) == q
        float df = qv - xv;
        lsum = fmaf(df, df, lsum);
    }
#pragma unroll
    for (int off = 32; off > 0; off >>= 1) lsum += __shfl_down(lsum, off, 64);
    if ((tid & 63) == 0) atomicAdd(loss, lsum * (0.5f / (float)TOT));
}

extern "C" void kernel_launch(void* const* d_in, const int* in_sizes, int n_in,
                              void* d_out, int out_size, void* d_ws, size_t ws_size,
                              hipStream_t stream) {
    const float* X = (const float*)d_in[0];   // [32, 256, 2048] fp32
    const float* E = (const float*)d_in[1];   // [1024, 256] fp32
    float* out = (float*)d_out;
    float* esq = (float*)d_ws;                // 4 KiB scratch
    float* loss = out + LOSS_OFF;
    float* idxf = out + IDX_OFF;

    hipMemsetAsync(loss, 0, sizeof(float), stream);
    esq_kernel<<<K_EMB / 4, 256, 0, stream>>>(E, esq);
    argmin_kernel<<<1024, 256, 0, stream>>>(X, E, esq, idxf);
    gather_kernel<<<2048, 256, 0, stream>>>(X, E, idxf, out, loss);
}

// Round 3
// 794.860 us; speedup vs baseline: 1.7289x; 1.7289x over previous
//
#include <hip/hip_runtime.h>
#include <math.h>

#define K_EMB 1024
#define D_DIM 256
#define T_SZ 2048
#define TOT 16777216        // B*D*T
#define LOSS_OFF 16777216
#define IDX_OFF 16777217

#define XSTR 280            // LDS row stride (bf16 units): 272 data + 8 pad (560 B = 35*16)
#define NDC 17              // 16 real d-chunks + 1 esq-fold chunk

typedef __attribute__((ext_vector_type(8)))  __bf16 bf16x8;
typedef __attribute__((ext_vector_type(8)))  short  s16x8;
typedef __attribute__((ext_vector_type(16))) float  f32x16;

__device__ __forceinline__ unsigned short f2bf(float f) {   // RNE fp32->bf16 bits
    unsigned u = __float_as_uint(f);
    u += 0x7FFFu + ((u >> 16) & 1u);
    return (unsigned short)(u >> 16);
}
__device__ __forceinline__ float bf2f(unsigned short h) {
    return __uint_as_float(((unsigned)h) << 16);
}
// top-2 insert, maximizing, tie -> smaller k (numpy first-occurrence argmin)
__device__ __forceinline__ void ins2(float& v1, int& k1, float& v2, int& k2,
                                     float v, int k) {
    bool b1 = (v > v1) || (v == v1 && k < k1);
    bool b2 = (v > v2) || (v == v2 && k < k2);
    if (b1) { v2 = v1; k2 = k1; v1 = v; k1 = k; }
    else if (b2) { v2 = v; k2 = k; }
}

// --- Kernel 0: per-code squared norms (fp32) ------------------------------
__global__ __launch_bounds__(256) void esq_kernel(const float* __restrict__ E,
                                                  float* __restrict__ esq) {
    int k = blockIdx.x * 4 + (threadIdx.x >> 6);
    int lane = threadIdx.x & 63;
    const float* er = E + (size_t)k * D_DIM;
    float s = 0.f;
#pragma unroll
    for (int i = 0; i < 4; ++i) { float v = er[lane + 64 * i]; s = fmaf(v, v, s); }
#pragma unroll
    for (int off = 32; off > 0; off >>= 1) s += __shfl_down(s, off, 64);
    if (lane == 0) esq[k] = s;
}

// --- Kernel 0b: pre-pack E into MFMA A-fragment order, split bf16 hi/lo ---
// Layout: frag (kc in 0..32, dc in 0..17, lane in 0..64) -> 8 consecutive bf16
// A[m= lane&31][kdim=(lane>>5)*8+j], code k = kc*32+m, d = dc*16+(lane>>5)*8+j.
// dc==16 is the esq-fold chunk: Ahi[256]=h, Ahi[257]=q, Alo[256]=l where
// h+l+q ~= -0.5*esq[k] (3-term bf16 split, err ~6e-7).
__global__ __launch_bounds__(256) void prepack_kernel(const float* __restrict__ E,
        const float* __restrict__ esq, unsigned short* __restrict__ Ehi,
        unsigned short* __restrict__ Elo) {
    int gid = blockIdx.x * 256 + threadIdx.x;        // == (kc*17+dc)*64 + lane
    if (gid >= 32 * NDC * 64) return;
    int lane = gid & 63;
    int dc = (gid >> 6) % NDC;
    int kc = gid / (NDC * 64);
    int m = lane & 31, dh = lane >> 5;
    int k = kc * 32 + m;
    unsigned short h8[8], l8[8];
#pragma unroll
    for (int j = 0; j < 8; ++j) { h8[j] = 0; l8[j] = 0; }
    if (dc < 16) {
        int d0 = dc * 16 + dh * 8;
        const float* ep = E + (size_t)k * D_DIM + d0;
#pragma unroll
        for (int j = 0; j < 8; ++j) {
            float e = ep[j];
            unsigned short hh = f2bf(e);
            h8[j] = hh;
            l8[j] = f2bf(e - bf2f(hh));
        }
    } else if (dh == 0) {
        float v = -0.5f * esq[k];
        unsigned short h = f2bf(v);
        float r1 = v - bf2f(h);
        unsigned short l = f2bf(r1);
        float r2 = r1 - bf2f(l);
        unsigned short q = f2bf(r2);
        h8[0] = h; h8[1] = q; l8[0] = l;
    }
    s16x8 hv, lv;
#pragma unroll
    for (int j = 0; j < 8; ++j) { hv[j] = (short)h8[j]; lv[j] = (short)l8[j]; }
    ((s16x8*)Ehi)[gid] = hv;
    ((s16x8*)Elo)[gid] = lv;
}

// --- Kernel 1: argmin via split-bf16 MFMA + fp64 near-tie refine ----------
// Block: 256 thr / 4 waves, tile 32 t. Wave w owns k in [w*256,(w+1)*256).
// D = A(E) x B(x): C/D col=lane&31 = t, row=(reg&3)+8*(reg>>2)+4*(lane>>5) = k%32.
__global__ __launch_bounds__(256, 4) void argmin_mfma_kernel(
        const float* __restrict__ X, const unsigned short* __restrict__ Ehi,
        const unsigned short* __restrict__ Elo, const float* __restrict__ E,
        float* __restrict__ idxf_out) {
    __shared__ unsigned short xh[32 * XSTR];   // 17.5 KB
    __shared__ unsigned short xl[32 * XSTR];   // 17.5 KB
    __shared__ float redv[4][32][2];
    __shared__ int   redk[4][32][2];

    int tid = threadIdx.x;
    int b = blockIdx.x >> 6;
    int t0 = (blockIdx.x & 63) << 5;

    // ---- stage X tile [32 t][256 d] -> bf16 hi/lo in LDS ----
    {
        int t = tid & 31;
        int dblk = tid >> 5;                   // 0..7, 32 d each
        const float* xp = X + (size_t)b * ((size_t)D_DIM * T_SZ) + t0 + t;
        for (int g = 0; g < 4; ++g) {
            int d0 = dblk * 32 + g * 8;
            s16x8 hv, lv;
#pragma unroll
            for (int j = 0; j < 8; ++j) {
                float xv = xp[(size_t)(d0 + j) * T_SZ];
                unsigned short hh = f2bf(xv);
                hv[j] = (short)hh;
                lv[j] = (short)f2bf(xv - bf2f(hh));
            }
            *(s16x8*)&xh[t * XSTR + d0] = hv;
            *(s16x8*)&xl[t * XSTR + d0] = lv;
        }
        if (tid < 32) {                        // esq-fold slots d=256..271
            s16x8 ones = {0, 0, 0, 0, 0, 0, 0, 0};
            ones[0] = (short)0x3F80; ones[1] = (short)0x3F80;   // bf16(1.0) x2
            s16x8 z = {0, 0, 0, 0, 0, 0, 0, 0};
            *(s16x8*)&xh[tid * XSTR + 256] = ones;
            *(s16x8*)&xh[tid * XSTR + 264] = z;
            *(s16x8*)&xl[tid * XSTR + 256] = z;
            *(s16x8*)&xl[tid * XSTR + 264] = z;
        }
    }
    __syncthreads();

    int lane = tid & 63;
    int w = tid >> 6;
    int mrow = lane & 31;
    int dhalf = lane >> 5;

    float v1s = -INFINITY, v2s = -INFINITY;
    int k1s = 0, k2s = 0;

    const s16x8* ehp = (const s16x8*)Ehi;
    const s16x8* elp = (const s16x8*)Elo;

    for (int kci = 0; kci < 8; ++kci) {
        int kcg = w * 8 + kci;                 // global 32-code chunk
        f32x16 acc;
#pragma unroll
        for (int i = 0; i < 16; ++i) acc[i] = 0.f;
#pragma unroll
        for (int dc = 0; dc < NDC; ++dc) {
            size_t abase = ((size_t)kcg * NDC + dc) * 64 + lane;
            bf16x8 ah = __builtin_bit_cast(bf16x8, ehp[abase]);
            bf16x8 al = __builtin_bit_cast(bf16x8, elp[abase]);
            int boff = dc * 16 + dhalf * 8;
            bf16x8 bh = __builtin_bit_cast(bf16x8, *(const s16x8*)&xh[mrow * XSTR + boff]);
            bf16x8 bl = __builtin_bit_cast(bf16x8, *(const s16x8*)&xl[mrow * XSTR + boff]);
            acc = __builtin_amdgcn_mfma_f32_32x32x16_bf16(ah, bh, acc, 0, 0, 0);
            acc = __builtin_amdgcn_mfma_f32_32x32x16_bf16(al, bh, acc, 0, 0, 0);
            acc = __builtin_amdgcn_mfma_f32_32x32x16_bf16(ah, bl, acc, 0, 0, 0);
        }
        int kbase = kcg * 32 + 4 * dhalf;
#pragma unroll
        for (int r = 0; r < 16; ++r) {
            int kk = kbase + (r & 3) + 8 * (r >> 2);   // ascending within lane
            ins2(v1s, k1s, v2s, k2s, acc[r], kk);
        }
    }

    // merge with lane^32 partner (same t, complementary k rows)
    {
        float pv1 = __shfl_xor(v1s, 32, 64); int pk1 = __shfl_xor(k1s, 32, 64);
        float pv2 = __shfl_xor(v2s, 32, 64); int pk2 = __shfl_xor(k2s, 32, 64);
        ins2(v1s, k1s, v2s, k2s, pv1, pk1);
        ins2(v1s, k1s, v2s, k2s, pv2, pk2);
    }
    if (dhalf == 0) {
        redv[w][mrow][0] = v1s; redk[w][mrow][0] = k1s;
        redv[w][mrow][1] = v2s; redk[w][mrow][1] = k2s;
    }
    __syncthreads();

    if (tid < 32) {
        int t = tid;
        float v1 = -INFINITY, v2 = -INFINITY;
        int k1 = 0, k2 = 0;
#pragma unroll
        for (int ww = 0; ww < 4; ++ww) {       // ascending k ranges
            ins2(v1, k1, v2, k2, redv[ww][t][0], redk[ww][t][0]);
            ins2(v1, k1, v2, k2, redv[ww][t][1], redk[ww][t][1]);
        }
        int kbest = k1;
        if (v1 - v2 < 0.005f) {                // s-gap = 2*m-gap < 1e-2 -> refine
            const float* e1 = E + (size_t)k1 * D_DIM;
            const float* e2 = E + (size_t)k2 * D_DIM;
            const float* xc = X + (size_t)b * ((size_t)D_DIM * T_SZ) + t0 + t;
            double d1 = 0.0, d2 = 0.0;
            for (int d = 0; d < D_DIM; ++d) {
                double xd = (double)xc[(size_t)d * T_SZ];
                double u1 = xd - (double)e1[d];
                double u2 = xd - (double)e2[d];
                d1 += u1 * u1;
                d2 += u2 * u2;
            }
            if (d2 < d1 || (d2 == d1 && k2 < k1)) kbest = k2;
        }
        idxf_out[(size_t)b * T_SZ + t0 + t] = (float)kbest;
    }
}

// --- Kernel 2: gather quantized, write out0 [B,D,T], commitment loss ------
// 32-t tile; E rows staged via 4 coalesced b32 loads/lane; LDS stride 257
// (odd dwords -> conflict-free column reads); coalesced X read / out write.
__global__ __launch_bounds__(256) void gather_kernel(const float* __restrict__ X,
        const float* __restrict__ E, const float* __restrict__ idxf_in,
        float* __restrict__ out0, float* __restrict__ loss) {
    __shared__ float q[32 * 257];              // 32.9 KB
    __shared__ int idxs[32];
    int tid = threadIdx.x;
    int b = blockIdx.x >> 6;
    int t0 = (blockIdx.x & 63) << 5;
    size_t n0 = (size_t)b * T_SZ + t0;

    if (tid < 32) idxs[tid] = (int)idxf_in[n0 + tid];
    __syncthreads();
    {
        int w = tid >> 6, lane = tid & 63;
        for (int rr = 0; rr < 8; ++rr) {
            int t = w * 8 + rr;
            int row = idxs[t];
            const float* ep = E + (size_t)row * D_DIM;
#pragma unroll
            for (int u = 0; u < 4; ++u)
                q[t * 257 + lane + 64 * u] = ep[lane + 64 * u];
        }
    }
    __syncthreads();
    {
        int t = tid & 31, dg = tid >> 5;
        size_t base = (size_t)b * ((size_t)D_DIM * T_SZ) + t0 + t;
        float lsum = 0.f;
        for (int d = dg; d < D_DIM; d += 8) {
            float qv = q[t * 257 + d];
            float xv = X[base + (size_t)d * T_SZ];
            out0[base + (size_t)d * T_SZ] = qv;  // STE: x + (q-x) == q
            float df = qv - xv;
            lsum = fmaf(df, df, lsum);
        }
#pragma unroll
        for (int off = 32; off > 0; off >>= 1) lsum += __shfl_down(lsum, off, 64);
        if ((tid & 63) == 0) atomicAdd(loss, lsum * (0.5f / (float)TOT));
    }
}

extern "C" void kernel_launch(void* const* d_in, const int* in_sizes, int n_in,
                              void* d_out, int out_size, void* d_ws, size_t ws_size,
                              hipStream_t stream) {
    const float* X = (const float*)d_in[0];   // [32, 256, 2048] fp32
    const float* E = (const float*)d_in[1];   // [1024, 256] fp32
    float* out = (float*)d_out;
    float* loss = out + LOSS_OFF;
    float* idxf = out + IDX_OFF;

    float* esq = (float*)d_ws;                                   // 4 KB
    unsigned short* Ehi = (unsigned short*)((char*)d_ws + 4096); // 557 KB
    unsigned short* Elo = (unsigned short*)((char*)d_ws + 4096 + 32 * NDC * 64 * 8 * 2);

    hipMemsetAsync(loss, 0, sizeof(float), stream);
    esq_kernel<<<K_EMB / 4, 256, 0, stream>>>(E, esq);
    prepack_kernel<<<(32 * NDC * 64) / 256, 256, 0, stream>>>(E, esq, Ehi, Elo);
    argmin_mfma_kernel<<<2048, 256, 0, stream>>>(X, Ehi, Elo, E, idxf);
    gather_kernel<<<2048, 256, 0, stream>>>(X, E, idxf, out, loss);
}

// Round 4
// 473.245 us; speedup vs baseline: 2.9039x; 1.6796x over previous
//
#include <hip/hip_runtime.h>
#include <math.h>

#define K_EMB 1024
#define D_DIM 256
#define T_SZ 2048
#define TOT 16777216        // B*D*T
#define LOSS_OFF 16777216
#define IDX_OFF 16777217
#define NDC 17              // 16 real d-chunks + 1 esq-fold chunk (A-side)

// dynamic LDS layout (bytes):           q-overlay (post-main): 128*257*4 = 131,584
#define SM_XH   0           // 65,536   x hi frags: [tc4][dc16][64 lanes][16B]
#define SM_XL   65536       // 65,536   x lo frags
#define SM_X2P  131072      //  2,048   per-thread x^2 partials (512 f32)
#define SM_REDV 133120      //  8,192   top2 vals [8w][4tc][32m][2]
#define SM_REDK 141312      //  8,192   top2 keys
#define SM_IDX  149504      //    512   idx per t
#define SM_TOT  150016

typedef __attribute__((ext_vector_type(8)))  __bf16 bf16x8;
typedef __attribute__((ext_vector_type(8)))  short  s16x8;
typedef __attribute__((ext_vector_type(16))) float  f32x16;

__device__ __forceinline__ unsigned short f2bf(float f) {   // RNE fp32->bf16 bits
    unsigned u = __float_as_uint(f);
    u += 0x7FFFu + ((u >> 16) & 1u);
    return (unsigned short)(u >> 16);
}
__device__ __forceinline__ float bf2f(unsigned short h) {
    return __uint_as_float(((unsigned)h) << 16);
}
// top-2 insert, maximizing, tie -> smaller k (numpy first-occurrence argmin)
__device__ __forceinline__ void ins2(float& v1, int& k1, float& v2, int& k2,
                                     float v, int k) {
    bool b1 = (v > v1) || (v == v1 && k < k1);
    bool b2 = (v > v2) || (v == v2 && k < k2);
    if (b1) { v2 = v1; k2 = k1; v1 = v; k1 = k; }
    else if (b2) { v2 = v; k2 = k; }
}

// --- Kernel 0: per-code squared norms (fp32) ------------------------------
__global__ __launch_bounds__(256) void esq_kernel(const float* __restrict__ E,
                                                  float* __restrict__ esq) {
    int k = blockIdx.x * 4 + (threadIdx.x >> 6);
    int lane = threadIdx.x & 63;
    const float* er = E + (size_t)k * D_DIM;
    float s = 0.f;
#pragma unroll
    for (int i = 0; i < 4; ++i) { float v = er[lane + 64 * i]; s = fmaf(v, v, s); }
#pragma unroll
    for (int off = 32; off > 0; off >>= 1) s += __shfl_down(s, off, 64);
    if (lane == 0) esq[k] = s;
}

// --- Kernel 0b: pre-pack E into MFMA A-frag order, split bf16 hi/lo -------
// frag (kc 0..32, dc 0..17, lane) -> 8 bf16: A[m=lane&31][kd=(lane>>5)*8+j],
// k = kc*32+m, d = dc*16+(lane>>5)*8+j. dc==16 = esq-fold (h,q in hi; l in lo).
__global__ __launch_bounds__(256) void prepack_kernel(const float* __restrict__ E,
        const float* __restrict__ esq, unsigned short* __restrict__ Ehi,
        unsigned short* __restrict__ Elo) {
    int gid = blockIdx.x * 256 + threadIdx.x;        // == (kc*17+dc)*64 + lane
    if (gid >= 32 * NDC * 64) return;
    int lane = gid & 63;
    int dc = (gid >> 6) % NDC;
    int kc = gid / (NDC * 64);
    int m = lane & 31, dh = lane >> 5;
    int k = kc * 32 + m;
    unsigned short h8[8], l8[8];
#pragma unroll
    for (int j = 0; j < 8; ++j) { h8[j] = 0; l8[j] = 0; }
    if (dc < 16) {
        int d0 = dc * 16 + dh * 8;
        const float* ep = E + (size_t)k * D_DIM + d0;
#pragma unroll
        for (int j = 0; j < 8; ++j) {
            float e = ep[j];
            unsigned short hh = f2bf(e);
            h8[j] = hh;
            l8[j] = f2bf(e - bf2f(hh));
        }
    } else if (dh == 0) {
        float v = -0.5f * esq[k];
        unsigned short h = f2bf(v);
        float r1 = v - bf2f(h);
        unsigned short l = f2bf(r1);
        float r2 = r1 - bf2f(l);
        unsigned short q = f2bf(r2);
        h8[0] = h; h8[1] = q; l8[0] = l;
    }
    s16x8 hv, lv;
#pragma unroll
    for (int j = 0; j < 8; ++j) { hv[j] = (short)h8[j]; lv[j] = (short)l8[j]; }
    ((s16x8*)Ehi)[gid] = hv;
    ((s16x8*)Elo)[gid] = lv;
}

// --- Fused kernel: argmin (split-bf16 MFMA) + loss + gather + out-write ---
// 512 thr / 8 waves; t-tile 128 (4 tc). Wave w owns kc quad [4w,4w+4) as
// 2 reg-groups of 2 -> acc[2][4] f32x16 = 128 VGPRs, no E redundancy.
__global__ __launch_bounds__(512, 2) void vq_fused_kernel(
        const float* __restrict__ X, const unsigned short* __restrict__ Ehi,
        const unsigned short* __restrict__ Elo, const float* __restrict__ E,
        float* __restrict__ out0, float* __restrict__ loss,
        float* __restrict__ idxf_out) {
    extern __shared__ char smem[];
    unsigned short* xhf = (unsigned short*)(smem + SM_XH);
    unsigned short* xlf = (unsigned short*)(smem + SM_XL);
    float* x2p = (float*)(smem + SM_X2P);
    float* redv = (float*)(smem + SM_REDV);
    int*   redk = (int*)(smem + SM_REDK);
    int*   idxs = (int*)(smem + SM_IDX);
    float* q    = (float*)smem;              // overlay after main loop

    int tid = threadIdx.x;
    int b = blockIdx.x >> 4;                 // 16 tiles of 128 t per b
    int tg0 = (blockIdx.x & 15) << 7;

    // ---- stage X tile [128 t][256 d] -> frag-order bf16 hi/lo in LDS ----
    {
        int t = tid & 127, dblk = tid >> 7;  // 4 dblk x 64 d
        int tc = t >> 5, m = t & 31;
        const float* xp = X + (size_t)b * ((size_t)D_DIM * T_SZ) + tg0 + t;
        float x2a = 0.f;
        for (int g = 0; g < 8; ++g) {
            int d0 = dblk * 64 + g * 8;
            s16x8 hv, lv;
#pragma unroll
            for (int j = 0; j < 8; ++j) {
                float xv = xp[(size_t)(d0 + j) * T_SZ];
                unsigned short hh = f2bf(xv);
                hv[j] = (short)hh;
                lv[j] = (short)f2bf(xv - bf2f(hh));
                x2a = fmaf(xv, xv, x2a);
            }
            int dc = d0 >> 4, h = (d0 >> 3) & 1;
            int fi = (tc * 16 + dc) * 64 + h * 32 + m;
            ((s16x8*)xhf)[fi] = hv;
            ((s16x8*)xlf)[fi] = lv;
        }
        x2p[tid] = x2a;
    }
    __syncthreads();

    int lane = tid & 63;
    int w = tid >> 6;                        // 0..7, owns kc in [4w, 4w+4)
    int dhalf = lane >> 5;

    const s16x8* ehp = (const s16x8*)Ehi;
    const s16x8* elp = (const s16x8*)Elo;
    const s16x8* bhf = (const s16x8*)xhf;
    const s16x8* blf = (const s16x8*)xlf;

    s16x8 bfold = {0, 0, 0, 0, 0, 0, 0, 0};
    if (dhalf == 0) { bfold[0] = (short)0x3F80; bfold[1] = (short)0x3F80; }
    bf16x8 bh_fold = __builtin_bit_cast(bf16x8, bfold);

    float v1s[4], v2s[4];
    int k1s[4], k2s[4];
#pragma unroll
    for (int tc = 0; tc < 4; ++tc) { v1s[tc] = -INFINITY; v2s[tc] = -INFINITY;
                                     k1s[tc] = 0; k2s[tc] = 0; }

    for (int kcg = 0; kcg < 2; ++kcg) {
        int kcb = w * 4 + kcg * 2;
        f32x16 acc[2][4];
#pragma unroll
        for (int kci = 0; kci < 2; ++kci)
#pragma unroll
            for (int tc = 0; tc < 4; ++tc)
#pragma unroll
                for (int i = 0; i < 16; ++i) acc[kci][tc][i] = 0.f;

#pragma unroll 1
        for (int dc = 0; dc < 16; ++dc) {
            size_t a0 = ((size_t)kcb * NDC + dc) * 64 + lane;
            bf16x8 ah0 = __builtin_bit_cast(bf16x8, ehp[a0]);
            bf16x8 al0 = __builtin_bit_cast(bf16x8, elp[a0]);
            bf16x8 ah1 = __builtin_bit_cast(bf16x8, ehp[a0 + NDC * 64]);
            bf16x8 al1 = __builtin_bit_cast(bf16x8, elp[a0 + NDC * 64]);
#pragma unroll
            for (int tc = 0; tc < 4; ++tc) {
                int fi = (tc * 16 + dc) * 64 + lane;
                bf16x8 bh = __builtin_bit_cast(bf16x8, bhf[fi]);
                bf16x8 bl = __builtin_bit_cast(bf16x8, blf[fi]);
                acc[0][tc] = __builtin_amdgcn_mfma_f32_32x32x16_bf16(ah0, bh, acc[0][tc], 0, 0, 0);
                acc[0][tc] = __builtin_amdgcn_mfma_f32_32x32x16_bf16(al0, bh, acc[0][tc], 0, 0, 0);
                acc[0][tc] = __builtin_amdgcn_mfma_f32_32x32x16_bf16(ah0, bl, acc[0][tc], 0, 0, 0);
                acc[1][tc] = __builtin_amdgcn_mfma_f32_32x32x16_bf16(ah1, bh, acc[1][tc], 0, 0, 0);
                acc[1][tc] = __builtin_amdgcn_mfma_f32_32x32x16_bf16(al1, bh, acc[1][tc], 0, 0, 0);
                acc[1][tc] = __builtin_amdgcn_mfma_f32_32x32x16_bf16(ah1, bl, acc[1][tc], 0, 0, 0);
            }
        }
        {   // esq-fold chunk (dc==16): B is constant, B-lo == 0
            size_t a0 = ((size_t)kcb * NDC + 16) * 64 + lane;
            bf16x8 ah0 = __builtin_bit_cast(bf16x8, ehp[a0]);
            bf16x8 al0 = __builtin_bit_cast(bf16x8, elp[a0]);
            bf16x8 ah1 = __builtin_bit_cast(bf16x8, ehp[a0 + NDC * 64]);
            bf16x8 al1 = __builtin_bit_cast(bf16x8, elp[a0 + NDC * 64]);
#pragma unroll
            for (int tc = 0; tc < 4; ++tc) {
                acc[0][tc] = __builtin_amdgcn_mfma_f32_32x32x16_bf16(ah0, bh_fold, acc[0][tc], 0, 0, 0);
                acc[0][tc] = __builtin_amdgcn_mfma_f32_32x32x16_bf16(al0, bh_fold, acc[0][tc], 0, 0, 0);
                acc[1][tc] = __builtin_amdgcn_mfma_f32_32x32x16_bf16(ah1, bh_fold, acc[1][tc], 0, 0, 0);
                acc[1][tc] = __builtin_amdgcn_mfma_f32_32x32x16_bf16(al1, bh_fold, acc[1][tc], 0, 0, 0);
            }
        }
        // scan acc -> per-tc top2 (ascending k: kci, then reg pattern)
#pragma unroll
        for (int kci = 0; kci < 2; ++kci) {
            int kb = (kcb + kci) * 32 + 4 * dhalf;
#pragma unroll
            for (int tc = 0; tc < 4; ++tc)
#pragma unroll
                for (int r = 0; r < 16; ++r) {
                    int kk = kb + (r & 3) + 8 * (r >> 2);
                    ins2(v1s[tc], k1s[tc], v2s[tc], k2s[tc], acc[kci][tc][r], kk);
                }
        }
    }

    // merge lane^32 partner (same t, complementary k rows), store to LDS
#pragma unroll
    for (int tc = 0; tc < 4; ++tc) {
        float pv1 = __shfl_xor(v1s[tc], 32, 64); int pk1 = __shfl_xor(k1s[tc], 32, 64);
        float pv2 = __shfl_xor(v2s[tc], 32, 64); int pk2 = __shfl_xor(k2s[tc], 32, 64);
        ins2(v1s[tc], k1s[tc], v2s[tc], k2s[tc], pv1, pk1);
        ins2(v1s[tc], k1s[tc], v2s[tc], k2s[tc], pv2, pk2);
        if (dhalf == 0) {
            int base = ((w * 4 + tc) * 32 + lane) * 2;
            redv[base] = v1s[tc];     redk[base] = k1s[tc];
            redv[base + 1] = v2s[tc]; redk[base + 1] = k2s[tc];
        }
    }
    __syncthreads();

    // per-t reduce across 8 waves (ascending k), refine, loss, idx
    if (tid < 128) {
        int t = tid, tc = t >> 5, m = t & 31;
        float v1 = -INFINITY, v2 = -INFINITY;
        int k1 = 0, k2 = 0;
#pragma unroll
        for (int ww = 0; ww < 8; ++ww) {
            int base = ((ww * 4 + tc) * 32 + m) * 2;
            ins2(v1, k1, v2, k2, redv[base], redk[base]);
            ins2(v1, k1, v2, k2, redv[base + 1], redk[base + 1]);
        }
        int kbest = k1;
        float dmin2;
        if (v1 - v2 < 0.005f) {   // near-tie: exact fp64 distances
            const float* e1 = E + (size_t)k1 * D_DIM;
            const float* e2 = E + (size_t)k2 * D_DIM;
            const float* xc = X + (size_t)b * ((size_t)D_DIM * T_SZ) + tg0 + t;
            double d1 = 0.0, d2 = 0.0;
            for (int d = 0; d < D_DIM; ++d) {
                double xd = (double)xc[(size_t)d * T_SZ];
                double u1 = xd - (double)e1[d];
                double u2 = xd - (double)e2[d];
                d1 += u1 * u1;
                d2 += u2 * u2;
            }
            if (d2 < d1 || (d2 == d1 && k2 < k1)) { kbest = k2; dmin2 = (float)d2; }
            else dmin2 = (float)d1;
        } else {
            float x2 = x2p[t] + x2p[128 + t] + x2p[256 + t] + x2p[384 + t];
            dmin2 = x2 - 2.0f * v1;   // ||x||^2 - 2(x.e - esq/2) = ||x-e||^2
        }
        idxs[t] = kbest;
        idxf_out[(size_t)b * T_SZ + tg0 + t] = (float)kbest;
        float lsum = dmin2;
#pragma unroll
        for (int off = 32; off > 0; off >>= 1) lsum += __shfl_down(lsum, off, 64);
        if ((tid & 63) == 0) atomicAdd(loss, lsum * (0.5f / (float)TOT));
    }
    __syncthreads();

    // gather E rows into q overlay (stride 257 -> conflict-free column reads)
    {
        for (int i = 0; i < 16; ++i) {
            int r = w * 16 + i;
            int row = idxs[r];
            const float* ep = E + (size_t)row * D_DIM;
#pragma unroll
            for (int u = 0; u < 4; ++u)
                q[r * 257 + lane + 64 * u] = ep[lane + 64 * u];
        }
    }
    __syncthreads();

    // write out0 [B,D,T]: lanes over t (coalesced), LDS reads conflict-free
    {
        int t = tid & 127, dgrp = tid >> 7;
        size_t obase = (size_t)b * ((size_t)D_DIM * T_SZ) + tg0 + t;
        for (int j = 0; j < 64; ++j) {
            int d = dgrp * 64 + j;
            out0[obase + (size_t)d * T_SZ] = q[t * 257 + d];
        }
    }
}

extern "C" void kernel_launch(void* const* d_in, const int* in_sizes, int n_in,
                              void* d_out, int out_size, void* d_ws, size_t ws_size,
                              hipStream_t stream) {
    const float* X = (const float*)d_in[0];   // [32, 256, 2048] fp32
    const float* E = (const float*)d_in[1];   // [1024, 256] fp32
    float* out = (float*)d_out;
    float* loss = out + LOSS_OFF;
    float* idxf = out + IDX_OFF;

    float* esq = (float*)d_ws;                                   // 4 KB
    unsigned short* Ehi = (unsigned short*)((char*)d_ws + 4096); // 544 KB
    unsigned short* Elo = (unsigned short*)((char*)d_ws + 4096 + 32 * NDC * 64 * 8 * 2);

    hipMemsetAsync(loss, 0, sizeof(float), stream);
    esq_kernel<<<K_EMB / 4, 256, 0, stream>>>(E, esq);
    prepack_kernel<<<(32 * NDC * 64 + 255) / 256, 256, 0, stream>>>(E, esq, Ehi, Elo);
    vq_fused_kernel<<<512, 512, SM_TOT, stream>>>(X, Ehi, Elo, E, out, loss, idxf);
}